// Round 7
// baseline (351.323 us; speedup 1.0000x reference)
//
#include <hip/hip_runtime.h>
#include <math.h>

#define DEVI __device__ __forceinline__

typedef short bf16x8 __attribute__((ext_vector_type(8)));   // 8 bf16 (4 VGPR) MFMA frag
typedef float f32x4 __attribute__((ext_vector_type(4)));
typedef float f32x16 __attribute__((ext_vector_type(16)));
typedef unsigned short u16x8 __attribute__((ext_vector_type(8)));
typedef unsigned short u16x4 __attribute__((ext_vector_type(4)));
typedef unsigned int u32x2 __attribute__((ext_vector_type(2)));
typedef int i32x4 __attribute__((ext_vector_type(4)));

static constexpr int S_LEN = 2048;
static constexpr int DMODEL = 1024;
static constexpr int NH = 16;
static constexpr int DK = 64;

// round-to-nearest-even fp32 -> bf16 bits
DEVI unsigned short f2bf(float f) {
  unsigned int u = __builtin_bit_cast(unsigned int, f);
  u = u + 0x7fffu + ((u >> 16) & 1u);
  return (unsigned short)(u >> 16);
}
DEVI unsigned cvtpk(float lo, float hi) {
  unsigned d;
  asm("v_cvt_pk_bf16_f32 %0, %1, %2" : "=v"(d) : "v"(lo), "v"(hi));
  return d;
}
DEVI float bitf(unsigned u) { return __builtin_bit_cast(float, u); }
DEVI unsigned bitu(float f) { return __builtin_bit_cast(unsigned, f); }

typedef __attribute__((address_space(3))) unsigned int lds_u32;
typedef __attribute__((address_space(1))) const unsigned int glb_u32;

// async global->LDS, 16B per lane; lds dest = wave-uniform base + lane*16
DEVI void gload16(const void* g, void* lds) {
  __builtin_amdgcn_global_load_lds((glb_u32*)reinterpret_cast<uintptr_t>(g),
                                   (lds_u32*)reinterpret_cast<uintptr_t>(lds),
                                   16, 0, 0);
}

// ---------------- fp32 -> bf16 convert (8 elems/thread) ----------------
__global__ __launch_bounds__(256) void cvt_f32_bf16(const float* __restrict__ in,
                                                    unsigned short* __restrict__ out,
                                                    int n8) {
  int i = blockIdx.x * 256 + threadIdx.x;
  if (i >= n8) return;
  const float4* p = (const float4*)in + (size_t)i * 2;
  float4 a = p[0], b = p[1];
  u16x8 o;
  o[0] = f2bf(a.x); o[1] = f2bf(a.y); o[2] = f2bf(a.z); o[3] = f2bf(a.w);
  o[4] = f2bf(b.x); o[5] = f2bf(b.y); o[6] = f2bf(b.z); o[7] = f2bf(b.w);
  *((u16x8*)out + i) = o;
}

// ---------------- projection GEMM: C[m,n] = (sum_k X[m,k]*W[n,k] + bias[n])*scale
// VT=0: out head layout [B,H,S,DK]; VT=1: transposed head layout [B,H,DK,S]
// (fused-Vt epilogue verified by the round-6 bisection).
template <int VT>
__global__ __launch_bounds__(256) void proj_gemm(const unsigned short* __restrict__ A,
                                                 const unsigned short* __restrict__ W,
                                                 const float* __restrict__ bias,
                                                 unsigned short* __restrict__ C,
                                                 float scale) {
  __shared__ unsigned short As[128 * 32];  // row-major [row][k], 64B rows (linear for gload)
  __shared__ unsigned short Bs[128 * 32];
  const int m0 = blockIdx.x * 128, n0 = blockIdx.y * 128;
  const int tid = threadIdx.x, wid = tid >> 6, lane = tid & 63;
  const int l15 = lane & 15, lg = lane >> 4;
  const int mb = (wid >> 1) * 64, nb = (wid & 1) * 64;

  f32x4 acc[4][4] = {};

  for (int kk = 0; kk < 32; ++kk) {
    const int k0 = kk * 32;  // element offset in K
#pragma unroll
    for (int i = 0; i < 2; ++i) {
      const int jbase = (wid * 2 + i) * 1024;      // byte base in 8KB tile
      const int o = jbase + lane * 16;             // this lane's byte offset
      const int row = o >> 6, inner = o & 63;      // 64B per row (32 bf16)
      gload16((const char*)A + (size_t)(m0 + row) * 2048 + k0 * 2 + inner,
              (char*)As + jbase);
      gload16((const char*)W + (size_t)(n0 + row) * 2048 + k0 * 2 + inner,
              (char*)Bs + jbase);
    }
    __syncthreads();

    bf16x8 af[4], bfr[4];
#pragma unroll
    for (int ms = 0; ms < 4; ++ms)
      af[ms] = *(const bf16x8*)&As[(mb + ms * 16 + l15) * 32 + lg * 8];
#pragma unroll
    for (int ns = 0; ns < 4; ++ns)
      bfr[ns] = *(const bf16x8*)&Bs[(nb + ns * 16 + l15) * 32 + lg * 8];
#pragma unroll
    for (int ms = 0; ms < 4; ++ms)
#pragma unroll
      for (int ns = 0; ns < 4; ++ns)
        acc[ms][ns] = __builtin_amdgcn_mfma_f32_16x16x32_bf16(af[ms], bfr[ns],
                                                              acc[ms][ns], 0, 0, 0);
    __syncthreads();
  }

  // epilogue scatter. C frag: row=(lg*4+r), col=l15.
#pragma unroll
  for (int ms = 0; ms < 4; ++ms) {
#pragma unroll
    for (int ns = 0; ns < 4; ++ns) {
      const int n = n0 + nb + ns * 16 + l15;
      const float bv = bias[n];
      const int mbase = m0 + mb + ms * 16 + lg * 4;
      if (VT) {
        // Vt[bh][dk][s]: r-dim (m = s) is contiguous -> pack 4 into one 8B store
        u16x4 pk4;
#pragma unroll
        for (int r = 0; r < 4; ++r) pk4[r] = f2bf((acc[ms][ns][r] + bv) * scale);
        const size_t oi =
            (((size_t)(mbase >> 11) * NH + (n >> 6)) * DK + (n & 63)) * S_LEN + (mbase & 2047);
        *(u16x4*)&C[oi] = pk4;
      } else {
#pragma unroll
        for (int r = 0; r < 4; ++r) {
          const int m = mbase + r;
          const size_t oi =
              (((size_t)(m >> 11) * NH + (n >> 6)) * S_LEN + (m & 2047)) * DK + (n & 63);
          C[oi] = f2bf((acc[ms][ns][r] + bv) * scale);
        }
      }
    }
  }
}

// ---------------- flash attention: round-3 compute, direct-global operands ---
// SINGLE-MECHANISM DELTA vs the round-6 passing kernel: every LDS read below is
// replaced by the byte-identical global dereference (staging swizzle cancels:
// LDS[R][c] held global[R][c ^ g(R)] and reads XORed g(R) back). LDS, staging,
// barriers, vmcnt drains deleted. Compute/softmax/fixup/epilogue are VERBATIM
// round 3/6 (passed at absmax 0.0029). Default launch bounds; no hand prefetch.
__global__ __launch_bounds__(256) void attn_fwd(const unsigned short* __restrict__ Q,
                                                const unsigned short* __restrict__ K,
                                                const unsigned short* __restrict__ Vt,
                                                float* __restrict__ Out) {
  // XCD-aware bijective swizzle: 1024 blocks = 8 XCDs x 128
  const int id = blockIdx.x;
  const int o = (id & 7) * 128 + (id >> 3);
  const int qt = o & 15, bh = o >> 4;

  const unsigned short* Qb = Q + (size_t)bh * S_LEN * DK;
  const char* Kb = (const char*)(K + (size_t)bh * S_LEN * DK);
  const char* Vb = (const char*)(Vt + (size_t)bh * DK * S_LEN);
  float* Ob = Out + (size_t)(bh >> 4) * S_LEN * DMODEL + (bh & 15) * DK;

  const int tid = threadIdx.x, w = tid >> 6, lane = tid & 63;
  const int l31 = lane & 31, hi = lane >> 5;
  const int q0 = qt * 128 + w * 32;

  // Q row in registers: qf[d] = Q[q=l31][dk = d*16 + hi*8 .. +7] (B-frag form)
  bf16x8 qf[4];
  {
    const unsigned short* qp = Qb + (size_t)(q0 + l31) * DK + hi * 8;
#pragma unroll
    for (int d = 0; d < 4; ++d) qf[d] = *(const bf16x8*)(qp + d * 16);
  }

  // per-lane operand row bases (replace LDS row bases; same bytes delivered)
  const char* kR0 = Kb + l31 * 128 + hi * 16;       // K[j0 + l31][dk (2d+hi)*8..]
  const char* kR1 = kR0 + 32 * 128;                 // K[j0 + 32 + l31][..]
  const char* vR0 = Vb + l31 * 4096 + hi * 16;      // Vt[dk=l31][j0 + (4jb+2ks+hi)*8..]
  const char* vR1 = vR0 + 131072;                   // Vt[dk=32+l31][..]

  f32x16 oacc0 = {}, oacc1 = {};   // O[q=crow(r,hi)][dk = l31 + 32*db]
  float m_r = 0.f;                 // running max (log2 units), spec-exp safe at 0
  float lacc[4] = {0.f, 0.f, 0.f, 0.f};

  for (int it = 0; it < 32; ++it) {
    const int ko = it * 8192;   // K tile byte stride (64 rows x 128B)
    const int vo = it * 128;    // Vt j-window byte stride (64 j x 2B)

    // swapped QK^T: lane holds S~[q=l31][32 j-vals] in log2 units
    f32x16 sac0 = {}, sac1 = {};
#pragma unroll
    for (int d = 0; d < 4; ++d) {
      bf16x8 k0 = *(const bf16x8*)(kR0 + ko + d * 32);
      bf16x8 k1 = *(const bf16x8*)(kR1 + ko + d * 32);
      sac0 = __builtin_amdgcn_mfma_f32_32x32x16_bf16(k0, qf[d], sac0, 0, 0, 0);
      sac1 = __builtin_amdgcn_mfma_f32_32x32x16_bf16(k1, qf[d], sac1, 0, 0, 0);
    }

    // tile max, balanced tree (independent of the speculative exps below)
    float mx[8];
#pragma unroll
    for (int i = 0; i < 8; ++i)
      mx[i] = fmaxf(fmaxf(sac0[2 * i], sac0[2 * i + 1]),
                    fmaxf(sac1[2 * i], sac1[2 * i + 1]));
    float pmA = fmaxf(fmaxf(mx[0], mx[1]), fmaxf(mx[2], mx[3]));
    float pmB = fmaxf(fmaxf(mx[4], mx[5]), fmaxf(mx[6], mx[7]));
    float pm = fmaxf(pmA, pmB);

    // speculative P = exp2(s - m_old); accumulate l into 4 rotating chains
#pragma unroll
    for (int r = 0; r < 16; ++r) {
      const float p = exp2f(sac0[r] - m_r);
      sac0[r] = p;
      lacc[r & 3] += p;
    }
#pragma unroll
    for (int r = 0; r < 16; ++r) {
      const float p = exp2f(sac1[r] - m_r);
      sac1[r] = p;
      lacc[r & 3] += p;
    }
    {
      u32x2 t = __builtin_amdgcn_permlane32_swap(bitu(pm), bitu(pm), false, false);
      pm = fmaxf(bitf(t[0]), bitf(t[1]));
    }

    // rare fixup: max grew > 8 (log2) -> rescale everything by 2^(m_old-m_new)
    if (__any(pm - m_r > 8.f)) {
      const float mn = fmaxf(m_r, pm);
      const float esc = exp2f(m_r - mn);
      m_r = mn;
#pragma unroll
      for (int i = 0; i < 4; ++i) lacc[i] *= esc;
#pragma unroll
      for (int r = 0; r < 16; ++r) { sac0[r] *= esc; sac1[r] *= esc; }
#pragma unroll
      for (int r = 0; r < 16; ++r) {
        const float er = __shfl(esc, ((r & 3) + 8 * (r >> 2)) + hi * 4);
        oacc0[r] *= er;
        oacc1[r] *= er;
      }
    }

    // pack P to bf16 + permlane redistribute to PV A-frags (T12), then PV
#pragma unroll
    for (int jb = 0; jb < 2; ++jb) {
      const f32x16& e = jb ? sac1 : sac0;
      unsigned pk[8];
#pragma unroll
      for (int m = 0; m < 8; ++m) pk[m] = cvtpk(e[2 * m], e[2 * m + 1]);
#pragma unroll
      for (int ks = 0; ks < 2; ++ks) {
        u32x2 s02 = __builtin_amdgcn_permlane32_swap(pk[4 * ks], pk[4 * ks + 2], false, false);
        u32x2 s13 = __builtin_amdgcn_permlane32_swap(pk[4 * ks + 1], pk[4 * ks + 3], false, false);
        i32x4 paw = {(int)s02[0], (int)s13[0], (int)s02[1], (int)s13[1]};
        bf16x8 pa = __builtin_bit_cast(bf16x8, paw);
        bf16x8 v0 = *(const bf16x8*)(vR0 + vo + (2 * jb + ks) * 32);
        bf16x8 v1 = *(const bf16x8*)(vR1 + vo + (2 * jb + ks) * 32);
        oacc0 = __builtin_amdgcn_mfma_f32_32x32x16_bf16(pa, v0, oacc0, 0, 0, 0);
        oacc1 = __builtin_amdgcn_mfma_f32_32x32x16_bf16(pa, v1, oacc1, 0, 0, 0);
      }
    }
  }

  // final l: horizontal + cross-half; normalize + store fp32
  float l_r = (lacc[0] + lacc[1]) + (lacc[2] + lacc[3]);
  {
    u32x2 t = __builtin_amdgcn_permlane32_swap(bitu(l_r), bitu(l_r), false, false);
    l_r = bitf(t[0]) + bitf(t[1]);
  }
  const float linv = 1.f / l_r;
#pragma unroll
  for (int r = 0; r < 16; ++r) {
    const int cr = (r & 3) + 8 * (r >> 2);
    const float li = __shfl(linv, cr + hi * 4);
    const int qg = q0 + cr + 4 * hi;
    float* op = Ob + (size_t)qg * DMODEL;
    op[l31] = oacc0[r] * li;
    op[32 + l31] = oacc1[r] * li;
  }
}

// ---------------- host launch ------------------------------------------------
extern "C" void kernel_launch(void* const* d_in, const int* in_sizes, int n_in,
                              void* d_out, int out_size, void* d_ws, size_t ws_size,
                              hipStream_t stream) {
  (void)in_sizes; (void)n_in; (void)out_size; (void)ws_size;
  const float* q_in = (const float*)d_in[0];
  const float* k_in = (const float*)d_in[1];
  const float* v_in = (const float*)d_in[2];
  const float* Wq = (const float*)d_in[3];
  const float* bq = (const float*)d_in[4];
  const float* Wk = (const float*)d_in[5];
  const float* bk = (const float*)d_in[6];
  const float* Wv = (const float*)d_in[7];
  const float* bv = (const float*)d_in[8];
  float* out = (float*)d_out;

  char* ws = (char*)d_ws;
  unsigned short* Xbf = (unsigned short*)(ws);                    // 16 MB
  unsigned short* Wbf = (unsigned short*)(ws + 16777216);         // 2 MB
  unsigned short* Qh  = (unsigned short*)(ws + 18874368);         // 16 MB
  unsigned short* Kh  = Qh + 8388608;                             // 16 MB
  unsigned short* Vt  = Kh + 8388608;                             // 16 MB [bh][dk][s]

  const int nX8 = (4 * S_LEN * DMODEL) / 8;   // 1048576
  const int nW8 = (DMODEL * DMODEL) / 8;      // 131072
  const dim3 gGemm(64, 8);

  // Q scale = (1/sqrt(dk)) * log2(e): softmax runs in exp2 domain
  const float qscale = 0.125f * 1.44269504088896340736f;

  cvt_f32_bf16<<<4096, 256, 0, stream>>>(q_in, Xbf, nX8);
  cvt_f32_bf16<<<512, 256, 0, stream>>>(Wq, Wbf, nW8);
  proj_gemm<0><<<gGemm, 256, 0, stream>>>(Xbf, Wbf, bq, Qh, qscale);

  cvt_f32_bf16<<<4096, 256, 0, stream>>>(k_in, Xbf, nX8);
  cvt_f32_bf16<<<512, 256, 0, stream>>>(Wk, Wbf, nW8);
  proj_gemm<0><<<gGemm, 256, 0, stream>>>(Xbf, Wbf, bk, Kh, 1.0f);

  cvt_f32_bf16<<<4096, 256, 0, stream>>>(v_in, Xbf, nX8);
  cvt_f32_bf16<<<512, 256, 0, stream>>>(Wv, Wbf, nW8);
  proj_gemm<1><<<gGemm, 256, 0, stream>>>(Xbf, Wbf, bv, Vt, 1.0f);  // writes Vt directly

  attn_fwd<<<1024, 256, 0, stream>>>(Qh, Kh, Vt, out);
}

// Round 8
// 244.707 us; speedup vs baseline: 1.4357x; 1.4357x over previous
//
#include <hip/hip_runtime.h>
#include <math.h>

#define DEVI __device__ __forceinline__

typedef short bf16x8 __attribute__((ext_vector_type(8)));   // 8 bf16 (4 VGPR) MFMA frag
typedef float f32x4 __attribute__((ext_vector_type(4)));
typedef float f32x16 __attribute__((ext_vector_type(16)));
typedef unsigned short u16x8 __attribute__((ext_vector_type(8)));
typedef unsigned short u16x4 __attribute__((ext_vector_type(4)));
typedef unsigned int u32x2 __attribute__((ext_vector_type(2)));
typedef int i32x4 __attribute__((ext_vector_type(4)));

static constexpr int S_LEN = 2048;
static constexpr int DMODEL = 1024;
static constexpr int NH = 16;
static constexpr int DK = 64;

// round-to-nearest-even fp32 -> bf16 bits
DEVI unsigned short f2bf(float f) {
  unsigned int u = __builtin_bit_cast(unsigned int, f);
  u = u + 0x7fffu + ((u >> 16) & 1u);
  return (unsigned short)(u >> 16);
}
DEVI unsigned cvtpk(float lo, float hi) {
  unsigned d;
  asm("v_cvt_pk_bf16_f32 %0, %1, %2" : "=v"(d) : "v"(lo), "v"(hi));
  return d;
}
DEVI float bitf(unsigned u) { return __builtin_bit_cast(float, u); }
DEVI unsigned bitu(float f) { return __builtin_bit_cast(unsigned, f); }

typedef __attribute__((address_space(3))) unsigned int lds_u32;
typedef __attribute__((address_space(1))) const unsigned int glb_u32;

// async global->LDS, 16B per lane; lds dest = wave-uniform base + lane*16
DEVI void gload16(const void* g, void* lds) {
  __builtin_amdgcn_global_load_lds((glb_u32*)reinterpret_cast<uintptr_t>(g),
                                   (lds_u32*)reinterpret_cast<uintptr_t>(lds),
                                   16, 0, 0);
}

// ---------------- fp32 -> bf16 convert (8 elems/thread) ----------------
__global__ __launch_bounds__(256) void cvt_f32_bf16(const float* __restrict__ in,
                                                    unsigned short* __restrict__ out,
                                                    int n8) {
  int i = blockIdx.x * 256 + threadIdx.x;
  if (i >= n8) return;
  const float4* p = (const float4*)in + (size_t)i * 2;
  float4 a = p[0], b = p[1];
  u16x8 o;
  o[0] = f2bf(a.x); o[1] = f2bf(a.y); o[2] = f2bf(a.z); o[3] = f2bf(a.w);
  o[4] = f2bf(b.x); o[5] = f2bf(b.y); o[6] = f2bf(b.z); o[7] = f2bf(b.w);
  *((u16x8*)out + i) = o;
}

// ---------------- projection GEMM: C[m,n] = (sum_k X[m,k]*W[n,k] + bias[n])*scale
// VT=0: out head layout [B,H,S,DK]; VT=1: transposed head layout [B,H,DK,S]
// (fused-Vt epilogue verified by the round-6 bisection).
template <int VT>
__global__ __launch_bounds__(256) void proj_gemm(const unsigned short* __restrict__ A,
                                                 const unsigned short* __restrict__ W,
                                                 const float* __restrict__ bias,
                                                 unsigned short* __restrict__ C,
                                                 float scale) {
  __shared__ unsigned short As[128 * 32];  // row-major [row][k], 64B rows (linear for gload)
  __shared__ unsigned short Bs[128 * 32];
  const int m0 = blockIdx.x * 128, n0 = blockIdx.y * 128;
  const int tid = threadIdx.x, wid = tid >> 6, lane = tid & 63;
  const int l15 = lane & 15, lg = lane >> 4;
  const int mb = (wid >> 1) * 64, nb = (wid & 1) * 64;

  f32x4 acc[4][4] = {};

  for (int kk = 0; kk < 32; ++kk) {
    const int k0 = kk * 32;  // element offset in K
#pragma unroll
    for (int i = 0; i < 2; ++i) {
      const int jbase = (wid * 2 + i) * 1024;      // byte base in 8KB tile
      const int o = jbase + lane * 16;             // this lane's byte offset
      const int row = o >> 6, inner = o & 63;      // 64B per row (32 bf16)
      gload16((const char*)A + (size_t)(m0 + row) * 2048 + k0 * 2 + inner,
              (char*)As + jbase);
      gload16((const char*)W + (size_t)(n0 + row) * 2048 + k0 * 2 + inner,
              (char*)Bs + jbase);
    }
    __syncthreads();

    bf16x8 af[4], bfr[4];
#pragma unroll
    for (int ms = 0; ms < 4; ++ms)
      af[ms] = *(const bf16x8*)&As[(mb + ms * 16 + l15) * 32 + lg * 8];
#pragma unroll
    for (int ns = 0; ns < 4; ++ns)
      bfr[ns] = *(const bf16x8*)&Bs[(nb + ns * 16 + l15) * 32 + lg * 8];
#pragma unroll
    for (int ms = 0; ms < 4; ++ms)
#pragma unroll
      for (int ns = 0; ns < 4; ++ns)
        acc[ms][ns] = __builtin_amdgcn_mfma_f32_16x16x32_bf16(af[ms], bfr[ns],
                                                              acc[ms][ns], 0, 0, 0);
    __syncthreads();
  }

  // epilogue scatter. C frag: row=(lg*4+r), col=l15.
#pragma unroll
  for (int ms = 0; ms < 4; ++ms) {
#pragma unroll
    for (int ns = 0; ns < 4; ++ns) {
      const int n = n0 + nb + ns * 16 + l15;
      const float bv = bias[n];
      const int mbase = m0 + mb + ms * 16 + lg * 4;
      if (VT) {
        // Vt[bh][dk][s]: r-dim (m = s) is contiguous -> pack 4 into one 8B store
        u16x4 pk4;
#pragma unroll
        for (int r = 0; r < 4; ++r) pk4[r] = f2bf((acc[ms][ns][r] + bv) * scale);
        const size_t oi =
            (((size_t)(mbase >> 11) * NH + (n >> 6)) * DK + (n & 63)) * S_LEN + (mbase & 2047);
        *(u16x4*)&C[oi] = pk4;
      } else {
#pragma unroll
        for (int r = 0; r < 4; ++r) {
          const int m = mbase + r;
          const size_t oi =
              (((size_t)(m >> 11) * NH + (n >> 6)) * S_LEN + (m & 2047)) * DK + (n & 63);
          C[oi] = f2bf((acc[ms][ns][r] + bv) * scale);
        }
      }
    }
  }
}

// ---------------- flash attention: round-6 compute + T4 counted-vmcnt schedule
// SINGLE-MECHANISM DELTA vs round-6 (passed, 145us): staging goes 3-buffer,
// 2-tiles-ahead, with s_waitcnt vmcnt(4) + raw s_barrier per iter (loads stay
// in flight across the barrier) instead of vmcnt(0)+__syncthreads full drain.
// Race audit: buffer (it+2)%3 was last READ in iter it-1, whose ds_reads are
// consumed (compiler lgkmcnt) before that iter's barrier; STAGE is issued
// after it in program order. vmcnt(4) retires the oldest 4 loads = tile it+1.
// sched_barrier(0) after each barrier blocks compiler hoisting (rule #18).
// Compute/softmax/fixup/epilogue are VERBATIM round 6.
__global__ __launch_bounds__(256) void attn_fwd(const unsigned short* __restrict__ Q,
                                                const unsigned short* __restrict__ K,
                                                const unsigned short* __restrict__ Vt,
                                                float* __restrict__ Out) {
  // XCD-aware bijective swizzle: 1024 blocks = 8 XCDs x 128
  const int id = blockIdx.x;
  const int o = (id & 7) * 128 + (id >> 3);
  const int qt = o & 15, bh = o >> 4;

  const unsigned short* Qb = Q + (size_t)bh * S_LEN * DK;
  const char* Kb = (const char*)(K + (size_t)bh * S_LEN * DK);
  const char* Vb = (const char*)(Vt + (size_t)bh * DK * S_LEN);
  float* Ob = Out + (size_t)(bh >> 4) * S_LEN * DMODEL + (bh & 15) * DK;

  __shared__ unsigned short Ks[3][64][64];  // [buf][j][dk], 128B rows, swizzled slots
  __shared__ unsigned short Vs[3][64][64];  // [buf][dk][j]

  const int tid = threadIdx.x, w = tid >> 6, lane = tid & 63;
  const int l31 = lane & 31, hi = lane >> 5;
  const int q0 = qt * 128 + w * 32;
  const int swzr = (l31 & 7) ^ (((l31 >> 3) & 3) << 1);  // read-side slot XOR

  // staging source byte-offset per sub-chunk i (inverse content swizzle)
  const int s8 = lane >> 3;
  int cs[2];
#pragma unroll
  for (int i = 0; i < 2; ++i)
    cs[i] = (((lane & 7) ^ s8) ^ (((w * 2 + i) & 3) << 1)) * 16;

  const int krow0 = w * 16;  // this wave's staging rows

  // stage tile t into buffer sb (4 gload_lds per wave)
  auto STAGE = [&](int sb, int t) {
    const int j0 = t * 64;
#pragma unroll
    for (int i = 0; i < 2; ++i) {
      gload16(Kb + (size_t)(j0 + krow0 + i * 8 + s8) * 128 + cs[i],
              (char*)&Ks[sb][krow0 + i * 8][0]);
      gload16(Vb + (size_t)(krow0 + i * 8 + s8) * 4096 + j0 * 2 + cs[i],
              (char*)&Vs[sb][krow0 + i * 8][0]);
    }
  };

  // Q row in registers: qf[d] = Q[q=l31][dk = d*16 + hi*8 .. +7] (B-frag form)
  bf16x8 qf[4];
  {
    const unsigned short* qp = Qb + (size_t)(q0 + l31) * DK + hi * 8;
#pragma unroll
    for (int d = 0; d < 4; ++d) qf[d] = *(const bf16x8*)(qp + d * 16);
  }

  f32x16 oacc0 = {}, oacc1 = {};   // O[q=crow(r,hi)][dk = l31 + 32*db]
  float m_r = 0.f;                 // running max (log2 units), spec-exp safe at 0
  float lacc[4] = {0.f, 0.f, 0.f, 0.f};

  // prologue: stage tiles 0,1; wait for tile 0 only (counted)
  STAGE(0, 0);
  STAGE(1, 1);
  asm volatile("s_waitcnt vmcnt(4)" ::: "memory");
  __builtin_amdgcn_s_barrier();
  __builtin_amdgcn_sched_barrier(0);

  int cur = 0;
  for (int it = 0; it < 32; ++it) {
    // issue tile it+2's loads into the third buffer (2-deep prefetch)
    if (it < 30) STAGE(cur == 0 ? 2 : cur - 1, it + 2);

    const char* ksb = (const char*)&Ks[cur][0][0];
    const char* vsb = (const char*)&Vs[cur][0][0];

    // swapped QK^T: lane holds S~[q=l31][32 j-vals] in log2 units
    f32x16 sac0 = {}, sac1 = {};
#pragma unroll
    for (int d = 0; d < 4; ++d) {
      bf16x8 k0 = *(const bf16x8*)(ksb + (size_t)(l31)*128 + (((2 * d + hi) ^ swzr) * 16));
      bf16x8 k1 = *(const bf16x8*)(ksb + (size_t)(32 + l31) * 128 + (((2 * d + hi) ^ swzr) * 16));
      sac0 = __builtin_amdgcn_mfma_f32_32x32x16_bf16(k0, qf[d], sac0, 0, 0, 0);
      sac1 = __builtin_amdgcn_mfma_f32_32x32x16_bf16(k1, qf[d], sac1, 0, 0, 0);
    }

    // tile max, balanced tree (independent of the speculative exps below)
    float mx[8];
#pragma unroll
    for (int i = 0; i < 8; ++i)
      mx[i] = fmaxf(fmaxf(sac0[2 * i], sac0[2 * i + 1]),
                    fmaxf(sac1[2 * i], sac1[2 * i + 1]));
    float pmA = fmaxf(fmaxf(mx[0], mx[1]), fmaxf(mx[2], mx[3]));
    float pmB = fmaxf(fmaxf(mx[4], mx[5]), fmaxf(mx[6], mx[7]));
    float pm = fmaxf(pmA, pmB);

    // speculative P = exp2(s - m_old); accumulate l into 4 rotating chains
#pragma unroll
    for (int r = 0; r < 16; ++r) {
      const float p = exp2f(sac0[r] - m_r);
      sac0[r] = p;
      lacc[r & 3] += p;
    }
#pragma unroll
    for (int r = 0; r < 16; ++r) {
      const float p = exp2f(sac1[r] - m_r);
      sac1[r] = p;
      lacc[r & 3] += p;
    }
    {
      u32x2 t = __builtin_amdgcn_permlane32_swap(bitu(pm), bitu(pm), false, false);
      pm = fmaxf(bitf(t[0]), bitf(t[1]));
    }

    // rare fixup: max grew > 8 (log2) -> rescale everything by 2^(m_old-m_new)
    if (__any(pm - m_r > 8.f)) {
      const float mn = fmaxf(m_r, pm);
      const float esc = exp2f(m_r - mn);
      m_r = mn;
#pragma unroll
      for (int i = 0; i < 4; ++i) lacc[i] *= esc;
#pragma unroll
      for (int r = 0; r < 16; ++r) { sac0[r] *= esc; sac1[r] *= esc; }
#pragma unroll
      for (int r = 0; r < 16; ++r) {
        const float er = __shfl(esc, ((r & 3) + 8 * (r >> 2)) + hi * 4);
        oacc0[r] *= er;
        oacc1[r] *= er;
      }
    }

    // pack P to bf16 + permlane redistribute to PV A-frags (T12), then PV
#pragma unroll
    for (int jb = 0; jb < 2; ++jb) {
      const f32x16& e = jb ? sac1 : sac0;
      unsigned pk[8];
#pragma unroll
      for (int m = 0; m < 8; ++m) pk[m] = cvtpk(e[2 * m], e[2 * m + 1]);
#pragma unroll
      for (int ks = 0; ks < 2; ++ks) {
        u32x2 s02 = __builtin_amdgcn_permlane32_swap(pk[4 * ks], pk[4 * ks + 2], false, false);
        u32x2 s13 = __builtin_amdgcn_permlane32_swap(pk[4 * ks + 1], pk[4 * ks + 3], false, false);
        i32x4 paw = {(int)s02[0], (int)s13[0], (int)s02[1], (int)s13[1]};
        bf16x8 pa = __builtin_bit_cast(bf16x8, paw);
        const int vslot = ((4 * jb + 2 * ks + hi) ^ swzr) * 16;
        bf16x8 v0 = *(const bf16x8*)(vsb + (size_t)(l31)*128 + vslot);
        bf16x8 v1 = *(const bf16x8*)(vsb + (size_t)(32 + l31) * 128 + vslot);
        oacc0 = __builtin_amdgcn_mfma_f32_32x32x16_bf16(pa, v0, oacc0, 0, 0, 0);
        oacc1 = __builtin_amdgcn_mfma_f32_32x32x16_bf16(pa, v1, oacc1, 0, 0, 0);
      }
    }

    // counted retire: tile it+1's loads (oldest 4) must be home; tile it+2's
    // 4 may stay in flight across the barrier. Full drain only at the tail.
    if (it < 30) {
      asm volatile("s_waitcnt vmcnt(4)" ::: "memory");
      __builtin_amdgcn_s_barrier();
      __builtin_amdgcn_sched_barrier(0);
    } else if (it == 30) {
      asm volatile("s_waitcnt vmcnt(0)" ::: "memory");
      __builtin_amdgcn_s_barrier();
      __builtin_amdgcn_sched_barrier(0);
    }
    cur = (cur == 2) ? 0 : cur + 1;
  }

  // final l: horizontal + cross-half; normalize + store fp32
  float l_r = (lacc[0] + lacc[1]) + (lacc[2] + lacc[3]);
  {
    u32x2 t = __builtin_amdgcn_permlane32_swap(bitu(l_r), bitu(l_r), false, false);
    l_r = bitf(t[0]) + bitf(t[1]);
  }
  const float linv = 1.f / l_r;
#pragma unroll
  for (int r = 0; r < 16; ++r) {
    const int cr = (r & 3) + 8 * (r >> 2);
    const float li = __shfl(linv, cr + hi * 4);
    const int qg = q0 + cr + 4 * hi;
    float* op = Ob + (size_t)qg * DMODEL;
    op[l31] = oacc0[r] * li;
    op[32 + l31] = oacc1[r] * li;
  }
}

// ---------------- host launch ------------------------------------------------
extern "C" void kernel_launch(void* const* d_in, const int* in_sizes, int n_in,
                              void* d_out, int out_size, void* d_ws, size_t ws_size,
                              hipStream_t stream) {
  (void)in_sizes; (void)n_in; (void)out_size; (void)ws_size;
  const float* q_in = (const float*)d_in[0];
  const float* k_in = (const float*)d_in[1];
  const float* v_in = (const float*)d_in[2];
  const float* Wq = (const float*)d_in[3];
  const float* bq = (const float*)d_in[4];
  const float* Wk = (const float*)d_in[5];
  const float* bk = (const float*)d_in[6];
  const float* Wv = (const float*)d_in[7];
  const float* bv = (const float*)d_in[8];
  float* out = (float*)d_out;

  char* ws = (char*)d_ws;
  unsigned short* Xbf = (unsigned short*)(ws);                    // 16 MB
  unsigned short* Wbf = (unsigned short*)(ws + 16777216);         // 2 MB
  unsigned short* Qh  = (unsigned short*)(ws + 18874368);         // 16 MB
  unsigned short* Kh  = Qh + 8388608;                             // 16 MB
  unsigned short* Vt  = Kh + 8388608;                             // 16 MB [bh][dk][s]

  const int nX8 = (4 * S_LEN * DMODEL) / 8;   // 1048576
  const int nW8 = (DMODEL * DMODEL) / 8;      // 131072
  const dim3 gGemm(64, 8);

  // Q scale = (1/sqrt(dk)) * log2(e): softmax runs in exp2 domain
  const float qscale = 0.125f * 1.44269504088896340736f;

  cvt_f32_bf16<<<4096, 256, 0, stream>>>(q_in, Xbf, nX8);
  cvt_f32_bf16<<<512, 256, 0, stream>>>(Wq, Wbf, nW8);
  proj_gemm<0><<<gGemm, 256, 0, stream>>>(Xbf, Wbf, bq, Qh, qscale);

  cvt_f32_bf16<<<4096, 256, 0, stream>>>(k_in, Xbf, nX8);
  cvt_f32_bf16<<<512, 256, 0, stream>>>(Wk, Wbf, nW8);
  proj_gemm<0><<<gGemm, 256, 0, stream>>>(Xbf, Wbf, bk, Kh, 1.0f);

  cvt_f32_bf16<<<4096, 256, 0, stream>>>(v_in, Xbf, nX8);
  cvt_f32_bf16<<<512, 256, 0, stream>>>(Wv, Wbf, nW8);
  proj_gemm<1><<<gGemm, 256, 0, stream>>>(Xbf, Wbf, bv, Vt, 1.0f);  // writes Vt directly

  attn_fwd<<<1024, 256, 0, stream>>>(Qh, Kh, Vt, out);
}

// Round 9
// 210.659 us; speedup vs baseline: 1.6677x; 1.1616x over previous
//
#include <hip/hip_runtime.h>
#include <math.h>

#define DEVI __device__ __forceinline__

typedef short bf16x8 __attribute__((ext_vector_type(8)));   // 8 bf16 (4 VGPR) MFMA frag
typedef float f32x4 __attribute__((ext_vector_type(4)));
typedef float f32x16 __attribute__((ext_vector_type(16)));
typedef unsigned short u16x8 __attribute__((ext_vector_type(8)));
typedef unsigned short u16x4 __attribute__((ext_vector_type(4)));
typedef unsigned int u32x2 __attribute__((ext_vector_type(2)));
typedef int i32x4 __attribute__((ext_vector_type(4)));

static constexpr int S_LEN = 2048;
static constexpr int DMODEL = 1024;
static constexpr int NH = 16;
static constexpr int DK = 64;

// round-to-nearest-even fp32 -> bf16 bits
DEVI unsigned short f2bf(float f) {
  unsigned int u = __builtin_bit_cast(unsigned int, f);
  u = u + 0x7fffu + ((u >> 16) & 1u);
  return (unsigned short)(u >> 16);
}
DEVI unsigned cvtpk(float lo, float hi) {
  unsigned d;
  asm("v_cvt_pk_bf16_f32 %0, %1, %2" : "=v"(d) : "v"(lo), "v"(hi));
  return d;
}
DEVI float bitf(unsigned u) { return __builtin_bit_cast(float, u); }
DEVI unsigned bitu(float f) { return __builtin_bit_cast(unsigned, f); }

// fast exp2: single v_exp_f32 via compiler-visible builtin (hazard-safe,
// unlike raw inline asm -- round-4 lesson). Fallback keeps the exp2 DOMAIN
// (host qscale is branch-independent; host/device evaluate __has_builtin
// in separate passes).
#if __has_builtin(__builtin_amdgcn_exp2f)
DEVI float fexp2(float x) { return __builtin_amdgcn_exp2f(x); }
#else
DEVI float fexp2(float x) { return __expf(x * 0.69314718055994531f); }
#endif

typedef __attribute__((address_space(3))) unsigned int lds_u32;
typedef __attribute__((address_space(1))) const unsigned int glb_u32;

// async global->LDS, 16B per lane; lds dest = wave-uniform base + lane*16
DEVI void gload16(const void* g, void* lds) {
  __builtin_amdgcn_global_load_lds((glb_u32*)reinterpret_cast<uintptr_t>(g),
                                   (lds_u32*)reinterpret_cast<uintptr_t>(lds),
                                   16, 0, 0);
}

// ---------------- fp32 -> bf16 convert (8 elems/thread) ----------------
__global__ __launch_bounds__(256) void cvt_f32_bf16(const float* __restrict__ in,
                                                    unsigned short* __restrict__ out,
                                                    int n8) {
  int i = blockIdx.x * 256 + threadIdx.x;
  if (i >= n8) return;
  const float4* p = (const float4*)in + (size_t)i * 2;
  float4 a = p[0], b = p[1];
  u16x8 o;
  o[0] = f2bf(a.x); o[1] = f2bf(a.y); o[2] = f2bf(a.z); o[3] = f2bf(a.w);
  o[4] = f2bf(b.x); o[5] = f2bf(b.y); o[6] = f2bf(b.z); o[7] = f2bf(b.w);
  *((u16x8*)out + i) = o;
}

// ---------------- projection GEMM: C[m,n] = (sum_k X[m,k]*W[n,k] + bias[n])*scale
// VT=0: out head layout [B,H,S,DK]; VT=1: transposed head layout [B,H,DK,S]
// (fused-Vt epilogue verified by the round-6 bisection).
template <int VT>
__global__ __launch_bounds__(256) void proj_gemm(const unsigned short* __restrict__ A,
                                                 const unsigned short* __restrict__ W,
                                                 const float* __restrict__ bias,
                                                 unsigned short* __restrict__ C,
                                                 float scale) {
  __shared__ unsigned short As[128 * 32];  // row-major [row][k], 64B rows (linear for gload)
  __shared__ unsigned short Bs[128 * 32];
  const int m0 = blockIdx.x * 128, n0 = blockIdx.y * 128;
  const int tid = threadIdx.x, wid = tid >> 6, lane = tid & 63;
  const int l15 = lane & 15, lg = lane >> 4;
  const int mb = (wid >> 1) * 64, nb = (wid & 1) * 64;

  f32x4 acc[4][4] = {};

  for (int kk = 0; kk < 32; ++kk) {
    const int k0 = kk * 32;  // element offset in K
#pragma unroll
    for (int i = 0; i < 2; ++i) {
      const int jbase = (wid * 2 + i) * 1024;      // byte base in 8KB tile
      const int o = jbase + lane * 16;             // this lane's byte offset
      const int row = o >> 6, inner = o & 63;      // 64B per row (32 bf16)
      gload16((const char*)A + (size_t)(m0 + row) * 2048 + k0 * 2 + inner,
              (char*)As + jbase);
      gload16((const char*)W + (size_t)(n0 + row) * 2048 + k0 * 2 + inner,
              (char*)Bs + jbase);
    }
    __syncthreads();

    bf16x8 af[4], bfr[4];
#pragma unroll
    for (int ms = 0; ms < 4; ++ms)
      af[ms] = *(const bf16x8*)&As[(mb + ms * 16 + l15) * 32 + lg * 8];
#pragma unroll
    for (int ns = 0; ns < 4; ++ns)
      bfr[ns] = *(const bf16x8*)&Bs[(nb + ns * 16 + l15) * 32 + lg * 8];
#pragma unroll
    for (int ms = 0; ms < 4; ++ms)
#pragma unroll
      for (int ns = 0; ns < 4; ++ns)
        acc[ms][ns] = __builtin_amdgcn_mfma_f32_16x16x32_bf16(af[ms], bfr[ns],
                                                              acc[ms][ns], 0, 0, 0);
    __syncthreads();
  }

  // epilogue scatter. C frag: row=(lg*4+r), col=l15.
#pragma unroll
  for (int ms = 0; ms < 4; ++ms) {
#pragma unroll
    for (int ns = 0; ns < 4; ++ns) {
      const int n = n0 + nb + ns * 16 + l15;
      const float bv = bias[n];
      const int mbase = m0 + mb + ms * 16 + lg * 4;
      if (VT) {
        // Vt[bh][dk][s]: r-dim (m = s) is contiguous -> pack 4 into one 8B store
        u16x4 pk4;
#pragma unroll
        for (int r = 0; r < 4; ++r) pk4[r] = f2bf((acc[ms][ns][r] + bv) * scale);
        const size_t oi =
            (((size_t)(mbase >> 11) * NH + (n >> 6)) * DK + (n & 63)) * S_LEN + (mbase & 2047);
        *(u16x4*)&C[oi] = pk4;
      } else {
#pragma unroll
        for (int r = 0; r < 4; ++r) {
          const int m = mbase + r;
          const size_t oi =
              (((size_t)(m >> 11) * NH + (n >> 6)) * S_LEN + (m & 2047)) * DK + (n & 63);
          C[oi] = f2bf((acc[ms][ns][r] + bv) * scale);
        }
      }
    }
  }
}

// ---------------- flash attention (round-6 kernel; ONLY exp2f -> fexp2) ------
// SINGLE-MECHANISM DELTA vs round 6 (passed, 145us): the 32 per-iter exps (and
// the rare fixup esc) use the 1-instruction native exp2 instead of the ~5-instr
// libm exp2f. Schedule reverted to round-6 2-buffer vmcnt(0)+__syncthreads
// (round-8 counted-vmcnt was neutral: T4 needs an 8-phase schedule to pay).
__global__ __launch_bounds__(256) void attn_fwd(const unsigned short* __restrict__ Q,
                                                const unsigned short* __restrict__ K,
                                                const unsigned short* __restrict__ Vt,
                                                float* __restrict__ Out) {
  // XCD-aware bijective swizzle: 1024 blocks = 8 XCDs x 128
  const int id = blockIdx.x;
  const int o = (id & 7) * 128 + (id >> 3);
  const int qt = o & 15, bh = o >> 4;

  const unsigned short* Qb = Q + (size_t)bh * S_LEN * DK;
  const char* Kb = (const char*)(K + (size_t)bh * S_LEN * DK);
  const char* Vb = (const char*)(Vt + (size_t)bh * DK * S_LEN);
  float* Ob = Out + (size_t)(bh >> 4) * S_LEN * DMODEL + (bh & 15) * DK;

  __shared__ unsigned short Ks[2][64][64];  // [buf][j][dk], 128B rows, swizzled slots
  __shared__ unsigned short Vs[2][64][64];  // [buf][dk][j]

  const int tid = threadIdx.x, w = tid >> 6, lane = tid & 63;
  const int l31 = lane & 31, hi = lane >> 5;
  const int q0 = qt * 128 + w * 32;
  const int swzr = (l31 & 7) ^ (((l31 >> 3) & 3) << 1);  // read-side slot XOR

  // staging source byte-offset per sub-chunk i (inverse content swizzle)
  const int s8 = lane >> 3;
  int cs[2];
#pragma unroll
  for (int i = 0; i < 2; ++i)
    cs[i] = (((lane & 7) ^ s8) ^ (((w * 2 + i) & 3) << 1)) * 16;

  // Q row in registers: qf[d] = Q[q=l31][dk = d*16 + hi*8 .. +7] (B-frag form)
  bf16x8 qf[4];
  {
    const unsigned short* qp = Qb + (size_t)(q0 + l31) * DK + hi * 8;
#pragma unroll
    for (int d = 0; d < 4; ++d) qf[d] = *(const bf16x8*)(qp + d * 16);
  }

  f32x16 oacc0 = {}, oacc1 = {};   // O[q=crow(r,hi)][dk = l31 + 32*db]
  float m_r = 0.f;                 // running max (log2 units), spec-exp safe at 0
  float lacc[4] = {0.f, 0.f, 0.f, 0.f};

  const int krow0 = w * 16;        // this wave's staging rows

  // prologue: stage tile 0 into buf 0
#pragma unroll
  for (int i = 0; i < 2; ++i) {
    gload16(Kb + (size_t)(krow0 + i * 8 + s8) * 128 + cs[i],
            (char*)&Ks[0][krow0 + i * 8][0]);
    gload16(Vb + (size_t)(krow0 + i * 8 + s8) * 4096 + cs[i],
            (char*)&Vs[0][krow0 + i * 8][0]);
  }
  asm volatile("s_waitcnt vmcnt(0)" ::: "memory");
  __syncthreads();

  int buf = 0;
  for (int it = 0; it < 32; ++it) {
    // issue next tile's loads early (hide HBM under compute)
    if (it < 31) {
      const int j0 = (it + 1) * 64;
#pragma unroll
      for (int i = 0; i < 2; ++i) {
        gload16(Kb + (size_t)(j0 + krow0 + i * 8 + s8) * 128 + cs[i],
                (char*)&Ks[buf ^ 1][krow0 + i * 8][0]);
        gload16(Vb + (size_t)(krow0 + i * 8 + s8) * 4096 + j0 * 2 + cs[i],
                (char*)&Vs[buf ^ 1][krow0 + i * 8][0]);
      }
    }
    const char* ksb = (const char*)&Ks[buf][0][0];
    const char* vsb = (const char*)&Vs[buf][0][0];

    // swapped QK^T: lane holds S~[q=l31][32 j-vals] in log2 units
    f32x16 sac0 = {}, sac1 = {};
#pragma unroll
    for (int d = 0; d < 4; ++d) {
      bf16x8 k0 = *(const bf16x8*)(ksb + (size_t)(l31)*128 + (((2 * d + hi) ^ swzr) * 16));
      bf16x8 k1 = *(const bf16x8*)(ksb + (size_t)(32 + l31) * 128 + (((2 * d + hi) ^ swzr) * 16));
      sac0 = __builtin_amdgcn_mfma_f32_32x32x16_bf16(k0, qf[d], sac0, 0, 0, 0);
      sac1 = __builtin_amdgcn_mfma_f32_32x32x16_bf16(k1, qf[d], sac1, 0, 0, 0);
    }

    // tile max, balanced tree (independent of the speculative exps below)
    float mx[8];
#pragma unroll
    for (int i = 0; i < 8; ++i)
      mx[i] = fmaxf(fmaxf(sac0[2 * i], sac0[2 * i + 1]),
                    fmaxf(sac1[2 * i], sac1[2 * i + 1]));
    float pmA = fmaxf(fmaxf(mx[0], mx[1]), fmaxf(mx[2], mx[3]));
    float pmB = fmaxf(fmaxf(mx[4], mx[5]), fmaxf(mx[6], mx[7]));
    float pm = fmaxf(pmA, pmB);

    // speculative P = exp2(s - m_old); accumulate l into 4 rotating chains
#pragma unroll
    for (int r = 0; r < 16; ++r) {
      const float p = fexp2(sac0[r] - m_r);
      sac0[r] = p;
      lacc[r & 3] += p;
    }
#pragma unroll
    for (int r = 0; r < 16; ++r) {
      const float p = fexp2(sac1[r] - m_r);
      sac1[r] = p;
      lacc[r & 3] += p;
    }
    {
      u32x2 t = __builtin_amdgcn_permlane32_swap(bitu(pm), bitu(pm), false, false);
      pm = fmaxf(bitf(t[0]), bitf(t[1]));
    }

    // rare fixup: max grew > 8 (log2) -> rescale everything by 2^(m_old-m_new)
    if (__any(pm - m_r > 8.f)) {
      const float mn = fmaxf(m_r, pm);
      const float esc = fexp2(m_r - mn);
      m_r = mn;
#pragma unroll
      for (int i = 0; i < 4; ++i) lacc[i] *= esc;
#pragma unroll
      for (int r = 0; r < 16; ++r) { sac0[r] *= esc; sac1[r] *= esc; }
#pragma unroll
      for (int r = 0; r < 16; ++r) {
        const float er = __shfl(esc, ((r & 3) + 8 * (r >> 2)) + hi * 4);
        oacc0[r] *= er;
        oacc1[r] *= er;
      }
    }

    // pack P to bf16 + permlane redistribute to PV A-frags (T12), then PV
#pragma unroll
    for (int jb = 0; jb < 2; ++jb) {
      const f32x16& e = jb ? sac1 : sac0;
      unsigned pk[8];
#pragma unroll
      for (int m = 0; m < 8; ++m) pk[m] = cvtpk(e[2 * m], e[2 * m + 1]);
#pragma unroll
      for (int ks = 0; ks < 2; ++ks) {
        u32x2 s02 = __builtin_amdgcn_permlane32_swap(pk[4 * ks], pk[4 * ks + 2], false, false);
        u32x2 s13 = __builtin_amdgcn_permlane32_swap(pk[4 * ks + 1], pk[4 * ks + 3], false, false);
        i32x4 paw = {(int)s02[0], (int)s13[0], (int)s02[1], (int)s13[1]};
        bf16x8 pa = __builtin_bit_cast(bf16x8, paw);
        const int vslot = ((4 * jb + 2 * ks + hi) ^ swzr) * 16;
        bf16x8 v0 = *(const bf16x8*)(vsb + (size_t)(l31)*128 + vslot);
        bf16x8 v1 = *(const bf16x8*)(vsb + (size_t)(32 + l31) * 128 + vslot);
        oacc0 = __builtin_amdgcn_mfma_f32_32x32x16_bf16(pa, v0, oacc0, 0, 0, 0);
        oacc1 = __builtin_amdgcn_mfma_f32_32x32x16_bf16(pa, v1, oacc1, 0, 0, 0);
      }
    }

    asm volatile("s_waitcnt vmcnt(0)" ::: "memory");
    __syncthreads();
    buf ^= 1;
  }

  // final l: horizontal + cross-half; normalize + store fp32
  float l_r = (lacc[0] + lacc[1]) + (lacc[2] + lacc[3]);
  {
    u32x2 t = __builtin_amdgcn_permlane32_swap(bitu(l_r), bitu(l_r), false, false);
    l_r = bitf(t[0]) + bitf(t[1]);
  }
  const float linv = 1.f / l_r;
#pragma unroll
  for (int r = 0; r < 16; ++r) {
    const int cr = (r & 3) + 8 * (r >> 2);
    const float li = __shfl(linv, cr + hi * 4);
    const int qg = q0 + cr + 4 * hi;
    float* op = Ob + (size_t)qg * DMODEL;
    op[l31] = oacc0[r] * li;
    op[32 + l31] = oacc1[r] * li;
  }
}

// ---------------- host launch ------------------------------------------------
extern "C" void kernel_launch(void* const* d_in, const int* in_sizes, int n_in,
                              void* d_out, int out_size, void* d_ws, size_t ws_size,
                              hipStream_t stream) {
  (void)in_sizes; (void)n_in; (void)out_size; (void)ws_size;
  const float* q_in = (const float*)d_in[0];
  const float* k_in = (const float*)d_in[1];
  const float* v_in = (const float*)d_in[2];
  const float* Wq = (const float*)d_in[3];
  const float* bq = (const float*)d_in[4];
  const float* Wk = (const float*)d_in[5];
  const float* bk = (const float*)d_in[6];
  const float* Wv = (const float*)d_in[7];
  const float* bv = (const float*)d_in[8];
  float* out = (float*)d_out;

  char* ws = (char*)d_ws;
  unsigned short* Xbf = (unsigned short*)(ws);                    // 16 MB
  unsigned short* Wbf = (unsigned short*)(ws + 16777216);         // 2 MB
  unsigned short* Qh  = (unsigned short*)(ws + 18874368);         // 16 MB
  unsigned short* Kh  = Qh + 8388608;                             // 16 MB
  unsigned short* Vt  = Kh + 8388608;                             // 16 MB [bh][dk][s]

  const int nX8 = (4 * S_LEN * DMODEL) / 8;   // 1048576
  const int nW8 = (DMODEL * DMODEL) / 8;      // 131072
  const dim3 gGemm(64, 8);

  // Q scale = (1/sqrt(dk)) * log2(e): softmax runs in exp2 domain
  // (domain is branch-independent of the fexp2 __has_builtin dispatch)
  const float qscale = 0.125f * 1.44269504088896340736f;

  cvt_f32_bf16<<<4096, 256, 0, stream>>>(q_in, Xbf, nX8);
  cvt_f32_bf16<<<512, 256, 0, stream>>>(Wq, Wbf, nW8);
  proj_gemm<0><<<gGemm, 256, 0, stream>>>(Xbf, Wbf, bq, Qh, qscale);

  cvt_f32_bf16<<<4096, 256, 0, stream>>>(k_in, Xbf, nX8);
  cvt_f32_bf16<<<512, 256, 0, stream>>>(Wk, Wbf, nW8);
  proj_gemm<0><<<gGemm, 256, 0, stream>>>(Xbf, Wbf, bk, Kh, 1.0f);

  cvt_f32_bf16<<<4096, 256, 0, stream>>>(v_in, Xbf, nX8);
  cvt_f32_bf16<<<512, 256, 0, stream>>>(Wv, Wbf, nW8);
  proj_gemm<1><<<gGemm, 256, 0, stream>>>(Xbf, Wbf, bv, Vt, 1.0f);  // writes Vt directly

  attn_fwd<<<1024, 256, 0, stream>>>(Qh, Kh, Vt, out);
}